// Round 15
// baseline (1160.457 us; speedup 1.0000x reference)
//
#include <hip/hip_runtime.h>

#define T_DIM 4096
#define K1    4096      // H (hidden)
#define I_DIM 11008
#define QMAXF 127.0f

typedef int v4i  __attribute__((ext_vector_type(4)));
typedef int v16i __attribute__((ext_vector_type(16)));

// ---------------- helpers ----------------

__device__ __forceinline__ void gload16(const void* g, void* l) {
  __builtin_amdgcn_global_load_lds((__attribute__((address_space(1))) unsigned int*)(g),
                                   (__attribute__((address_space(3))) unsigned int*)(l),
                                   16, 0, 0);
}

__device__ __forceinline__ int packq(float a, float b, float c, float d) {
  return ((int)a & 255) | (((int)b & 255) << 8) | (((int)c & 255) << 16) | (((int)d & 255) << 24);
}

#define MFMA32(A, B, C) __builtin_amdgcn_mfma_i32_32x32x32_i8(A, B, C, 0, 0, 0)

// ---------------- pass 1: absmax(x) ----------------

__global__ void absmax_x_kernel(const float4* __restrict__ x4, unsigned* __restrict__ maxbits, int n4) {
  int tid = blockIdx.x * blockDim.x + threadIdx.x;
  int stride = gridDim.x * blockDim.x;
  float m = 0.f;
  for (int i = tid; i < n4; i += stride) {
    float4 v = x4[i];
    m = fmaxf(m, fmaxf(fmaxf(fabsf(v.x), fabsf(v.y)), fmaxf(fabsf(v.z), fabsf(v.w))));
  }
  #pragma unroll
  for (int off = 32; off; off >>= 1) m = fmaxf(m, __shfl_xor(m, off));
  if ((threadIdx.x & 63) == 0) atomicMax(maxbits, __float_as_uint(m));
}

// ---------------- pass 2: quantize x ----------------

__global__ void quant_x_kernel(const float4* __restrict__ x4, v4i* __restrict__ q4,
                               const unsigned* __restrict__ scal) {
  const float sx = __uint_as_float(scal[0]) * (1.0f / QMAXF);
  const long i = (long)blockIdx.x * blockDim.x + threadIdx.x;  // 16 floats per thread
  v4i o;
  #pragma unroll
  for (int j = 0; j < 4; ++j) {
    float4 v = x4[i * 4 + j];
    float a = fminf(fmaxf(rintf(v.x / sx), -QMAXF), QMAXF);
    float b = fminf(fmaxf(rintf(v.y / sx), -QMAXF), QMAXF);
    float c = fminf(fmaxf(rintf(v.z / sx), -QMAXF), QMAXF);
    float d = fminf(fmaxf(rintf(v.w / sx), -QMAXF), QMAXF);
    o[j] = packq(a, b, c, d);
  }
  q4[i] = o;
}

// ---------------- weight f32(int-valued) -> int8 ----------------

__global__ void conv_w_kernel(const float4* __restrict__ w4, v4i* __restrict__ q4) {
  const long i = (long)blockIdx.x * blockDim.x + threadIdx.x;  // 16 floats per thread
  v4i o;
  #pragma unroll
  for (int j = 0; j < 4; ++j) {
    float4 v = w4[i * 4 + j];
    o[j] = packq(rintf(v.x), rintf(v.y), rintf(v.z), rintf(v.w));
  }
  q4[i] = o;
}

// ================= R11 structure, compiler-scheduled phase waits =================
// 256x256 tile (256 T-rows x 256 staged B-rows), BK=64.
// 512 thr = 8 waves (4M x 2N), per-wave 64 rows x 128 staged cols, acc[2][4] v16i.
// LDS: 4-buffer ring x (A 16KB + B 16KB) = 128 KB. Tile layout [kslot:4][row:256][16B].
// Distance-3 prefetch, steady-state vmcnt(8), never 0 until drain.
// Per tile 2 phases: {6x ds_read_b128; 2x gload; barrier; prio1; 8 MFMA; prio0}.
// SINGLE-VARIABLE DELTA vs R11: the manual {lgkmcnt(0); sched_barrier(0)} pair is
// REMOVED -- hipcc emits fine-grained counted lgkmcnt per MFMA operand (m97), so the
// first MFMA starts as soon as its own reads land instead of after all 6.

// ---------------- GEMM1 fused: int8 GEMM + dequant + silu*mul + h absmax ----------------

__global__ __launch_bounds__(512, 2)
void gemm1_silu_kernel(const signed char* __restrict__ qx,
                       const signed char* __restrict__ w8,
                       const float* __restrict__ sgu,
                       unsigned* __restrict__ scal,
                       float* __restrict__ hbuf)
{
  __shared__ signed char L[4][32768];   // per buf: A [0,16384), B [16384,32768)

  const int tid  = threadIdx.x;
  const int lane = tid & 63;
  const int wid  = tid >> 6;       // 0..7
  const int wr   = wid >> 1;       // 0..3  (64-row band)
  const int wc   = wid & 1;        // 0..1  (128 staged-B rows)
  const int l31  = lane & 31;
  const int kgl  = lane >> 5;

  // XCD-chunked bijective swizzle (1376 = 8*172); brow fastest -> B panel L2-resident
  const int lin = blockIdx.x;
  const int sw  = (lin & 7) * 172 + (lin >> 3);
  const int brow = (sw & 15) * 256;
  const int bcol = (sw >> 4) * 128;            // h-col base (128 per block)

  // staging: thread covers staged row sr=tid&255, sub-kslot sk=tid>>8
  const int sr = tid & 255, sk = tid >> 8;
  const signed char* gA = qx + (size_t)(brow + sr) * K1 + sk * 16;
  const int grp = sr >> 6, w = sr & 63;
  const int gcolw = bcol + grp * 32 + (w & 31);
  const size_t srcrow = (w < 32) ? (size_t)gcolw : (size_t)(I_DIM + gcolw);
  const signed char* gB = w8 + srcrow * K1 + sk * 16;
  const int lA = tid * 16;             // + 8192 for upper kslot pair
  const int lB = 16384 + tid * 16;

  // fragment bases: [kslot][row][16B]; kslot = 2*ks + kgl
  const int ab = (wr * 64 + l31) * 16;
  const int bb = 16384 + (wc * 128 + l31) * 16;

  v16i zero = {0};
  v16i acc[2][4];
  #pragma unroll
  for (int m = 0; m < 2; ++m)
    #pragma unroll
    for (int n = 0; n < 4; ++n) acc[m][n] = zero;

  const int nk = K1 / 64;  // 64
  // prologue: stage tiles 0,1,2 (4 gloads each)
  #pragma unroll
  for (int t = 0; t < 3; ++t) {
    gload16(gA + t * 64,      &L[t][lA]);
    gload16(gA + t * 64 + 32, &L[t][lA + 8192]);
    gload16(gB + t * 64,      &L[t][lB]);
    gload16(gB + t * 64 + 32, &L[t][lB + 8192]);
  }

  for (int t = 0; t < nk; ++t) {
    if (t + 2 < nk)      asm volatile("s_waitcnt vmcnt(8)" ::: "memory");
    else if (t + 1 < nk) asm volatile("s_waitcnt vmcnt(4)" ::: "memory");
    else                 asm volatile("s_waitcnt vmcnt(0)" ::: "memory");
    __builtin_amdgcn_s_barrier();
    asm volatile("" ::: "memory");
    const signed char* Lb = L[t & 3];
    signed char* Ls = L[(t + 3) & 3];
    const bool st = (t + 3) < nk;
    const int ko = (t + 3) * 64;

    // ---- phase 0 (ks=0): compiler-inserted counted lgkmcnt ----
    {
      v4i af0, af1, bf0, bf1, bf2, bf3;
      af0 = *(const v4i*)&Lb[kgl * 4096 + ab];
      af1 = *(const v4i*)&Lb[kgl * 4096 + ab + 512];
      bf0 = *(const v4i*)&Lb[kgl * 4096 + bb];
      bf1 = *(const v4i*)&Lb[kgl * 4096 + bb + 512];
      bf2 = *(const v4i*)&Lb[kgl * 4096 + bb + 1024];
      bf3 = *(const v4i*)&Lb[kgl * 4096 + bb + 1536];
      if (st) {
        gload16(gA + ko,      &Ls[lA]);
        gload16(gA + ko + 32, &Ls[lA + 8192]);
      }
      __builtin_amdgcn_s_barrier();
      __builtin_amdgcn_s_setprio(1);
      acc[0][0] = MFMA32(af0, bf0, acc[0][0]);
      acc[0][1] = MFMA32(af0, bf1, acc[0][1]);
      acc[0][2] = MFMA32(af0, bf2, acc[0][2]);
      acc[0][3] = MFMA32(af0, bf3, acc[0][3]);
      acc[1][0] = MFMA32(af1, bf0, acc[1][0]);
      acc[1][1] = MFMA32(af1, bf1, acc[1][1]);
      acc[1][2] = MFMA32(af1, bf2, acc[1][2]);
      acc[1][3] = MFMA32(af1, bf3, acc[1][3]);
      __builtin_amdgcn_s_setprio(0);
    }

    // ---- phase 1 (ks=1): compiler-inserted counted lgkmcnt ----
    {
      v4i af0, af1, bf0, bf1, bf2, bf3;
      af0 = *(const v4i*)&Lb[(2 + kgl) * 4096 + ab];
      af1 = *(const v4i*)&Lb[(2 + kgl) * 4096 + ab + 512];
      bf0 = *(const v4i*)&Lb[(2 + kgl) * 4096 + bb];
      bf1 = *(const v4i*)&Lb[(2 + kgl) * 4096 + bb + 512];
      bf2 = *(const v4i*)&Lb[(2 + kgl) * 4096 + bb + 1024];
      bf3 = *(const v4i*)&Lb[(2 + kgl) * 4096 + bb + 1536];
      if (st) {
        gload16(gB + ko,      &Ls[lB]);
        gload16(gB + ko + 32, &Ls[lB + 8192]);
      }
      __builtin_amdgcn_s_barrier();
      __builtin_amdgcn_s_setprio(1);
      acc[0][0] = MFMA32(af0, bf0, acc[0][0]);
      acc[0][1] = MFMA32(af0, bf1, acc[0][1]);
      acc[0][2] = MFMA32(af0, bf2, acc[0][2]);
      acc[0][3] = MFMA32(af0, bf3, acc[0][3]);
      acc[1][0] = MFMA32(af1, bf0, acc[1][0]);
      acc[1][1] = MFMA32(af1, bf1, acc[1][1]);
      acc[1][2] = MFMA32(af1, bf2, acc[1][2]);
      acc[1][3] = MFMA32(af1, bf3, acc[1][3]);
      __builtin_amdgcn_s_setprio(0);
    }
  }

  // epilogue: dequant + silu*mul, write h, track max|h|
  // C layout (32x32): col(lane)=l31, row = (q&3) + 8*(q>>2) + 4*kgl
  // n-frag pairs: (0,1)=gate/up @ grp wc*2, (2,3)=gate/up @ grp wc*2+1
  const float xsc = __uint_as_float(scal[0]) * (1.0f / QMAXF);
  float hmax = 0.f;
  #pragma unroll
  for (int m = 0; m < 2; ++m) {
    const int rbase = brow + wr * 64 + m * 32 + 4 * kgl;
    #pragma unroll
    for (int p = 0; p < 2; ++p) {
      const int col = bcol + (wc * 2 + p) * 32 + l31;
      const float sg = sgu[col] * xsc;
      const float su = sgu[I_DIM + col] * xsc;
      #pragma unroll
      for (int q = 0; q < 16; ++q) {
        const int row = rbase + (q & 3) + 8 * (q >> 2);
        float g = (float)acc[m][2 * p][q] * sg;
        float u = (float)acc[m][2 * p + 1][q] * su;
        float hv = (g / (1.f + expf(-g))) * u;
        hmax = fmaxf(hmax, fabsf(hv));
        hbuf[(size_t)row * I_DIM + col] = hv;
      }
    }
  }
  #pragma unroll
  for (int off = 32; off; off >>= 1) hmax = fmaxf(hmax, __shfl_xor(hmax, off));
  if (lane == 0) atomicMax(scal + 1, __float_as_uint(hmax));
}

// ---------------- quantize h (+ emit h_scale) ----------------

__global__ void quant_h_kernel(const float4* __restrict__ h4, v4i* __restrict__ q4,
                               const unsigned* __restrict__ scal, float* __restrict__ hs_out) {
  const float hs = __uint_as_float(scal[1]) * (1.0f / QMAXF);
  const long i = (long)blockIdx.x * blockDim.x + threadIdx.x;
  if (i == 0) hs_out[0] = hs;
  v4i o;
  #pragma unroll
  for (int j = 0; j < 4; ++j) {
    float4 v = h4[i * 4 + j];
    float a = fminf(fmaxf(rintf(v.x / hs), -QMAXF), QMAXF);
    float b = fminf(fmaxf(rintf(v.y / hs), -QMAXF), QMAXF);
    float c = fminf(fmaxf(rintf(v.z / hs), -QMAXF), QMAXF);
    float d = fminf(fmaxf(rintf(v.w / hs), -QMAXF), QMAXF);
    o[j] = packq(a, b, c, d);
  }
  q4[i] = o;
}

// ---------------- GEMM2: out = (qh @ wdn^T) * (h_scale * s_down) ----------------
// 256x256 tile, BK=64, same structure as gemm1. Grid 256 = 1 block/CU.

__global__ __launch_bounds__(512, 2)
void gemm2_kernel(const signed char* __restrict__ qh,
                  const signed char* __restrict__ w8,
                  const float* __restrict__ sdn,
                  const unsigned* __restrict__ scal,
                  float* __restrict__ out)
{
  __shared__ signed char L[4][32768];

  const int tid  = threadIdx.x;
  const int lane = tid & 63;
  const int wid  = tid >> 6;
  const int wr   = wid >> 1;       // 0..3
  const int wc   = wid & 1;        // 0..1
  const int l31  = lane & 31;
  const int kgl  = lane >> 5;

  const int lin = blockIdx.x;                  // 0..255 = 8*32
  const int sw  = (lin & 7) * 32 + (lin >> 3);
  const int brow = (sw & 15) * 256;
  const int bcol = (sw >> 4) * 256;

  const int sr = tid & 255, sk = tid >> 8;
  const signed char* gA = qh + (size_t)(brow + sr) * I_DIM + sk * 16;
  const signed char* gB = w8 + (size_t)(bcol + sr) * I_DIM + sk * 16;
  const int lA = tid * 16;
  const int lB = 16384 + tid * 16;

  const int ab = (wr * 64 + l31) * 16;
  const int bb = 16384 + (wc * 128 + l31) * 16;

  v16i zero = {0};
  v16i acc[2][4];
  #pragma unroll
  for (int m = 0; m < 2; ++m)
    #pragma unroll
    for (int n = 0; n < 4; ++n) acc[m][n] = zero;

  const int nk = I_DIM / 64;  // 172
  #pragma unroll
  for (int t = 0; t < 3; ++t) {
    gload16(gA + t * 64,      &L[t][lA]);
    gload16(gA + t * 64 + 32, &L[t][lA + 8192]);
    gload16(gB + t * 64,      &L[t][lB]);
    gload16(gB + t * 64 + 32, &L[t][lB + 8192]);
  }

  for (int t = 0; t < nk; ++t) {
    if (t + 2 < nk)      asm volatile("s_waitcnt vmcnt(8)" ::: "memory");
    else if (t + 1 < nk) asm volatile("s_waitcnt vmcnt(4)" ::: "memory");
    else                 asm volatile("s_waitcnt vmcnt(0)" ::: "memory");
    __builtin_amdgcn_s_barrier();
    asm volatile("" ::: "memory");
    const signed char* Lb = L[t & 3];
    signed char* Ls = L[(t + 3) & 3];
    const bool st = (t + 3) < nk;
    const int ko = (t + 3) * 64;

    // ---- phase 0 (ks=0) ----
    {
      v4i af0, af1, bf0, bf1, bf2, bf3;
      af0 = *(const v4i*)&Lb[kgl * 4096 + ab];
      af1 = *(const v4i*)&Lb[kgl * 4096 + ab + 512];
      bf0 = *(const v4i*)&Lb[kgl * 4096 + bb];
      bf1 = *(const v4i*)&Lb[kgl * 4096 + bb + 512];
      bf2 = *(const v4i*)&Lb[kgl * 4096 + bb + 1024];
      bf3 = *(const v4i*)&Lb[kgl * 4096 + bb + 1536];
      if (st) {
        gload16(gA + ko,      &Ls[lA]);
        gload16(gA + ko + 32, &Ls[lA + 8192]);
      }
      __builtin_amdgcn_s_barrier();
      __builtin_amdgcn_s_setprio(1);
      acc[0][0] = MFMA32(af0, bf0, acc[0][0]);
      acc[0][1] = MFMA32(af0, bf1, acc[0][1]);
      acc[0][2] = MFMA32(af0, bf2, acc[0][2]);
      acc[0][3] = MFMA32(af0, bf3, acc[0][3]);
      acc[1][0] = MFMA32(af1, bf0, acc[1][0]);
      acc[1][1] = MFMA32(af1, bf1, acc[1][1]);
      acc[1][2] = MFMA32(af1, bf2, acc[1][2]);
      acc[1][3] = MFMA32(af1, bf3, acc[1][3]);
      __builtin_amdgcn_s_setprio(0);
    }

    // ---- phase 1 (ks=1) ----
    {
      v4i af0, af1, bf0, bf1, bf2, bf3;
      af0 = *(const v4i*)&Lb[(2 + kgl) * 4096 + ab];
      af1 = *(const v4i*)&Lb[(2 + kgl) * 4096 + ab + 512];
      bf0 = *(const v4i*)&Lb[(2 + kgl) * 4096 + bb];
      bf1 = *(const v4i*)&Lb[(2 + kgl) * 4096 + bb + 512];
      bf2 = *(const v4i*)&Lb[(2 + kgl) * 4096 + bb + 1024];
      bf3 = *(const v4i*)&Lb[(2 + kgl) * 4096 + bb + 1536];
      if (st) {
        gload16(gB + ko,      &Ls[lB]);
        gload16(gB + ko + 32, &Ls[lB + 8192]);
      }
      __builtin_amdgcn_s_barrier();
      __builtin_amdgcn_s_setprio(1);
      acc[0][0] = MFMA32(af0, bf0, acc[0][0]);
      acc[0][1] = MFMA32(af0, bf1, acc[0][1]);
      acc[0][2] = MFMA32(af0, bf2, acc[0][2]);
      acc[0][3] = MFMA32(af0, bf3, acc[0][3]);
      acc[1][0] = MFMA32(af1, bf0, acc[1][0]);
      acc[1][1] = MFMA32(af1, bf1, acc[1][1]);
      acc[1][2] = MFMA32(af1, bf2, acc[1][2]);
      acc[1][3] = MFMA32(af1, bf3, acc[1][3]);
      __builtin_amdgcn_s_setprio(0);
    }
  }

  const float hsc = __uint_as_float(scal[1]) * (1.0f / QMAXF);
  #pragma unroll
  for (int m = 0; m < 2; ++m) {
    const int rbase = brow + wr * 64 + m * 32 + 4 * kgl;
    #pragma unroll
    for (int n = 0; n < 4; ++n) {
      const int col = bcol + wc * 128 + n * 32 + l31;
      const float s = sdn[col] * hsc;
      #pragma unroll
      for (int q = 0; q < 16; ++q) {
        const int row = rbase + (q & 3) + 8 * (q >> 2);
        out[(size_t)row * K1 + col] = (float)acc[m][n][q] * s;
      }
    }
  }
}

// ---------------- launch ----------------

extern "C" void kernel_launch(void* const* d_in, const int* in_sizes, int n_in,
                              void* d_out, int out_size, void* d_ws, size_t ws_size,
                              hipStream_t stream) {
  (void)in_sizes; (void)n_in; (void)out_size; (void)ws_size;
  const float* x   = (const float*)d_in[0];
  const float* wgu = (const float*)d_in[1];
  const float* sgu = (const float*)d_in[2];
  const float* wdn = (const float*)d_in[3];
  const float* sdn = (const float*)d_in[4];
  float* out = (float*)d_out;
  char* ws = (char*)d_ws;

  // ws layout (16B aligned): total ~360 MB
  signed char* qx  = (signed char*)(ws + 0LL);           // 16,777,216
  signed char* w8g = (signed char*)(ws + 16777216LL);    // 90,177,536
  signed char* w8d = (signed char*)(ws + 106954752LL);   // 45,088,768
  signed char* qh  = (signed char*)(ws + 152043520LL);   // 45,088,768
  float*       hb  = (float*)      (ws + 197132288LL);   // 180,355,072
  unsigned*    scal= (unsigned*)   (ws + 377487360LL);   // 256

  hipMemsetAsync(scal, 0, 256, stream);
  absmax_x_kernel<<<2048, 256, 0, stream>>>((const float4*)x, scal, T_DIM * K1 / 4);
  quant_x_kernel<<<4096, 256, 0, stream>>>((const float4*)x, (v4i*)qx, scal);
  conv_w_kernel<<<22016, 256, 0, stream>>>((const float4*)wgu, (v4i*)w8g);
  conv_w_kernel<<<11008, 256, 0, stream>>>((const float4*)wdn, (v4i*)w8d);

  gemm1_silu_kernel<<<1376, 512, 0, stream>>>(qx, w8g, sgu, scal, hb);

  quant_h_kernel<<<11008, 256, 0, stream>>>((const float4*)hb, (v4i*)qh, scal,
                                            out + (size_t)T_DIM * K1);

  gemm2_kernel<<<256, 512, 0, stream>>>(qh, w8d, sdn, scal, out);
}

// Round 16
// 1158.485 us; speedup vs baseline: 1.0017x; 1.0017x over previous
//
#include <hip/hip_runtime.h>

#define T_DIM 4096
#define K1    4096      // H (hidden)
#define I_DIM 11008
#define QMAXF 127.0f

typedef int v4i  __attribute__((ext_vector_type(4)));
typedef int v16i __attribute__((ext_vector_type(16)));

// ---------------- helpers ----------------

__device__ __forceinline__ void gload16(const void* g, void* l) {
  __builtin_amdgcn_global_load_lds((__attribute__((address_space(1))) unsigned int*)(g),
                                   (__attribute__((address_space(3))) unsigned int*)(l),
                                   16, 0, 0);
}

__device__ __forceinline__ int packq(float a, float b, float c, float d) {
  return ((int)a & 255) | (((int)b & 255) << 8) | (((int)c & 255) << 16) | (((int)d & 255) << 24);
}

#define MFMA32(A, B, C) __builtin_amdgcn_mfma_i32_32x32x32_i8(A, B, C, 0, 0, 0)

// ---------------- pass 1: absmax(x) ----------------

__global__ void absmax_x_kernel(const float4* __restrict__ x4, unsigned* __restrict__ maxbits, int n4) {
  int tid = blockIdx.x * blockDim.x + threadIdx.x;
  int stride = gridDim.x * blockDim.x;
  float m = 0.f;
  for (int i = tid; i < n4; i += stride) {
    float4 v = x4[i];
    m = fmaxf(m, fmaxf(fmaxf(fabsf(v.x), fabsf(v.y)), fmaxf(fabsf(v.z), fabsf(v.w))));
  }
  #pragma unroll
  for (int off = 32; off; off >>= 1) m = fmaxf(m, __shfl_xor(m, off));
  if ((threadIdx.x & 63) == 0) atomicMax(maxbits, __float_as_uint(m));
}

// ---------------- pass 2: quantize x ----------------

__global__ void quant_x_kernel(const float4* __restrict__ x4, v4i* __restrict__ q4,
                               const unsigned* __restrict__ scal) {
  const float sx = __uint_as_float(scal[0]) * (1.0f / QMAXF);
  const long i = (long)blockIdx.x * blockDim.x + threadIdx.x;  // 16 floats per thread
  v4i o;
  #pragma unroll
  for (int j = 0; j < 4; ++j) {
    float4 v = x4[i * 4 + j];
    float a = fminf(fmaxf(rintf(v.x / sx), -QMAXF), QMAXF);
    float b = fminf(fmaxf(rintf(v.y / sx), -QMAXF), QMAXF);
    float c = fminf(fmaxf(rintf(v.z / sx), -QMAXF), QMAXF);
    float d = fminf(fmaxf(rintf(v.w / sx), -QMAXF), QMAXF);
    o[j] = packq(a, b, c, d);
  }
  q4[i] = o;
}

// ---------------- weight f32(int-valued) -> int8 ----------------

__global__ void conv_w_kernel(const float4* __restrict__ w4, v4i* __restrict__ q4) {
  const long i = (long)blockIdx.x * blockDim.x + threadIdx.x;  // 16 floats per thread
  v4i o;
  #pragma unroll
  for (int j = 0; j < 4; ++j) {
    float4 v = w4[i * 4 + j];
    o[j] = packq(rintf(v.x), rintf(v.y), rintf(v.z), rintf(v.w));
  }
  q4[i] = o;
}

// ================= best-known GEMM structure (locked in, R11/R15) =================
// 256x256 tile (256 T-rows x 256 staged B-rows), BK=64.
// 512 thr = 8 waves (4M x 2N), per-wave 64 rows x 128 staged cols, acc[2][4] v16i.
// LDS: 4-buffer ring x (A 16KB + B 16KB) = 128 KB. Tile layout [kslot:4][row:256][16B].
// Distance-3 prefetch, steady-state vmcnt(8) (never 0 until drain).
// Per tile 2 phases: {6x ds_read_b128; 2x gload; barrier; prio1; 8 MFMA; prio0}
// with compiler-emitted counted lgkmcnt (manual lgkm0 proven neutral, R15).
// Session record: 11 structural variants (R2-R15) all converge ~2.2 POPS;
// this configuration reproduced at 1158.5-1160.5 us total (gemm1 ~665 us =
// 2.22 POPS = ~50% of the 4.4 POPS i8 MFMA ceiling). Terminal plateau.

// ---------------- GEMM1 fused: int8 GEMM + dequant + silu*mul + h absmax ----------------

__global__ __launch_bounds__(512, 2)
void gemm1_silu_kernel(const signed char* __restrict__ qx,
                       const signed char* __restrict__ w8,
                       const float* __restrict__ sgu,
                       unsigned* __restrict__ scal,
                       float* __restrict__ hbuf)
{
  __shared__ signed char L[4][32768];   // per buf: A [0,16384), B [16384,32768)

  const int tid  = threadIdx.x;
  const int lane = tid & 63;
  const int wid  = tid >> 6;       // 0..7
  const int wr   = wid >> 1;       // 0..3  (64-row band)
  const int wc   = wid & 1;        // 0..1  (128 staged-B rows)
  const int l31  = lane & 31;
  const int kgl  = lane >> 5;

  // XCD-chunked bijective swizzle (1376 = 8*172); brow fastest -> B panel L2-resident
  const int lin = blockIdx.x;
  const int sw  = (lin & 7) * 172 + (lin >> 3);
  const int brow = (sw & 15) * 256;
  const int bcol = (sw >> 4) * 128;            // h-col base (128 per block)

  // staging: thread covers staged row sr=tid&255, sub-kslot sk=tid>>8
  const int sr = tid & 255, sk = tid >> 8;
  const signed char* gA = qx + (size_t)(brow + sr) * K1 + sk * 16;
  const int grp = sr >> 6, w = sr & 63;
  const int gcolw = bcol + grp * 32 + (w & 31);
  const size_t srcrow = (w < 32) ? (size_t)gcolw : (size_t)(I_DIM + gcolw);
  const signed char* gB = w8 + srcrow * K1 + sk * 16;
  const int lA = tid * 16;             // + 8192 for upper kslot pair
  const int lB = 16384 + tid * 16;

  // fragment bases: [kslot][row][16B]; kslot = 2*ks + kgl
  const int ab = (wr * 64 + l31) * 16;
  const int bb = 16384 + (wc * 128 + l31) * 16;

  v16i zero = {0};
  v16i acc[2][4];
  #pragma unroll
  for (int m = 0; m < 2; ++m)
    #pragma unroll
    for (int n = 0; n < 4; ++n) acc[m][n] = zero;

  const int nk = K1 / 64;  // 64
  // prologue: stage tiles 0,1,2 (4 gloads each)
  #pragma unroll
  for (int t = 0; t < 3; ++t) {
    gload16(gA + t * 64,      &L[t][lA]);
    gload16(gA + t * 64 + 32, &L[t][lA + 8192]);
    gload16(gB + t * 64,      &L[t][lB]);
    gload16(gB + t * 64 + 32, &L[t][lB + 8192]);
  }

  for (int t = 0; t < nk; ++t) {
    if (t + 2 < nk)      asm volatile("s_waitcnt vmcnt(8)" ::: "memory");
    else if (t + 1 < nk) asm volatile("s_waitcnt vmcnt(4)" ::: "memory");
    else                 asm volatile("s_waitcnt vmcnt(0)" ::: "memory");
    __builtin_amdgcn_s_barrier();
    asm volatile("" ::: "memory");
    const signed char* Lb = L[t & 3];
    signed char* Ls = L[(t + 3) & 3];
    const bool st = (t + 3) < nk;
    const int ko = (t + 3) * 64;

    // ---- phase 0 (ks=0) ----
    {
      v4i af0, af1, bf0, bf1, bf2, bf3;
      af0 = *(const v4i*)&Lb[kgl * 4096 + ab];
      af1 = *(const v4i*)&Lb[kgl * 4096 + ab + 512];
      bf0 = *(const v4i*)&Lb[kgl * 4096 + bb];
      bf1 = *(const v4i*)&Lb[kgl * 4096 + bb + 512];
      bf2 = *(const v4i*)&Lb[kgl * 4096 + bb + 1024];
      bf3 = *(const v4i*)&Lb[kgl * 4096 + bb + 1536];
      if (st) {
        gload16(gA + ko,      &Ls[lA]);
        gload16(gA + ko + 32, &Ls[lA + 8192]);
      }
      __builtin_amdgcn_s_barrier();
      __builtin_amdgcn_s_setprio(1);
      acc[0][0] = MFMA32(af0, bf0, acc[0][0]);
      acc[0][1] = MFMA32(af0, bf1, acc[0][1]);
      acc[0][2] = MFMA32(af0, bf2, acc[0][2]);
      acc[0][3] = MFMA32(af0, bf3, acc[0][3]);
      acc[1][0] = MFMA32(af1, bf0, acc[1][0]);
      acc[1][1] = MFMA32(af1, bf1, acc[1][1]);
      acc[1][2] = MFMA32(af1, bf2, acc[1][2]);
      acc[1][3] = MFMA32(af1, bf3, acc[1][3]);
      __builtin_amdgcn_s_setprio(0);
    }

    // ---- phase 1 (ks=1) ----
    {
      v4i af0, af1, bf0, bf1, bf2, bf3;
      af0 = *(const v4i*)&Lb[(2 + kgl) * 4096 + ab];
      af1 = *(const v4i*)&Lb[(2 + kgl) * 4096 + ab + 512];
      bf0 = *(const v4i*)&Lb[(2 + kgl) * 4096 + bb];
      bf1 = *(const v4i*)&Lb[(2 + kgl) * 4096 + bb + 512];
      bf2 = *(const v4i*)&Lb[(2 + kgl) * 4096 + bb + 1024];
      bf3 = *(const v4i*)&Lb[(2 + kgl) * 4096 + bb + 1536];
      if (st) {
        gload16(gB + ko,      &Ls[lB]);
        gload16(gB + ko + 32, &Ls[lB + 8192]);
      }
      __builtin_amdgcn_s_barrier();
      __builtin_amdgcn_s_setprio(1);
      acc[0][0] = MFMA32(af0, bf0, acc[0][0]);
      acc[0][1] = MFMA32(af0, bf1, acc[0][1]);
      acc[0][2] = MFMA32(af0, bf2, acc[0][2]);
      acc[0][3] = MFMA32(af0, bf3, acc[0][3]);
      acc[1][0] = MFMA32(af1, bf0, acc[1][0]);
      acc[1][1] = MFMA32(af1, bf1, acc[1][1]);
      acc[1][2] = MFMA32(af1, bf2, acc[1][2]);
      acc[1][3] = MFMA32(af1, bf3, acc[1][3]);
      __builtin_amdgcn_s_setprio(0);
    }
  }

  // epilogue: dequant + silu*mul, write h, track max|h|
  // C layout (32x32): col(lane)=l31, row = (q&3) + 8*(q>>2) + 4*kgl
  // n-frag pairs: (0,1)=gate/up @ grp wc*2, (2,3)=gate/up @ grp wc*2+1
  const float xsc = __uint_as_float(scal[0]) * (1.0f / QMAXF);
  float hmax = 0.f;
  #pragma unroll
  for (int m = 0; m < 2; ++m) {
    const int rbase = brow + wr * 64 + m * 32 + 4 * kgl;
    #pragma unroll
    for (int p = 0; p < 2; ++p) {
      const int col = bcol + (wc * 2 + p) * 32 + l31;
      const float sg = sgu[col] * xsc;
      const float su = sgu[I_DIM + col] * xsc;
      #pragma unroll
      for (int q = 0; q < 16; ++q) {
        const int row = rbase + (q & 3) + 8 * (q >> 2);
        float g = (float)acc[m][2 * p][q] * sg;
        float u = (float)acc[m][2 * p + 1][q] * su;
        float hv = (g / (1.f + expf(-g))) * u;
        hmax = fmaxf(hmax, fabsf(hv));
        hbuf[(size_t)row * I_DIM + col] = hv;
      }
    }
  }
  #pragma unroll
  for (int off = 32; off; off >>= 1) hmax = fmaxf(hmax, __shfl_xor(hmax, off));
  if (lane == 0) atomicMax(scal + 1, __float_as_uint(hmax));
}

// ---------------- quantize h (+ emit h_scale) ----------------

__global__ void quant_h_kernel(const float4* __restrict__ h4, v4i* __restrict__ q4,
                               const unsigned* __restrict__ scal, float* __restrict__ hs_out) {
  const float hs = __uint_as_float(scal[1]) * (1.0f / QMAXF);
  const long i = (long)blockIdx.x * blockDim.x + threadIdx.x;
  if (i == 0) hs_out[0] = hs;
  v4i o;
  #pragma unroll
  for (int j = 0; j < 4; ++j) {
    float4 v = h4[i * 4 + j];
    float a = fminf(fmaxf(rintf(v.x / hs), -QMAXF), QMAXF);
    float b = fminf(fmaxf(rintf(v.y / hs), -QMAXF), QMAXF);
    float c = fminf(fmaxf(rintf(v.z / hs), -QMAXF), QMAXF);
    float d = fminf(fmaxf(rintf(v.w / hs), -QMAXF), QMAXF);
    o[j] = packq(a, b, c, d);
  }
  q4[i] = o;
}

// ---------------- GEMM2: out = (qh @ wdn^T) * (h_scale * s_down) ----------------
// 256x256 tile, BK=64, same structure as gemm1. Grid 256 = 1 block/CU.

__global__ __launch_bounds__(512, 2)
void gemm2_kernel(const signed char* __restrict__ qh,
                  const signed char* __restrict__ w8,
                  const float* __restrict__ sdn,
                  const unsigned* __restrict__ scal,
                  float* __restrict__ out)
{
  __shared__ signed char L[4][32768];

  const int tid  = threadIdx.x;
  const int lane = tid & 63;
  const int wid  = tid >> 6;
  const int wr   = wid >> 1;       // 0..3
  const int wc   = wid & 1;        // 0..1
  const int l31  = lane & 31;
  const int kgl  = lane >> 5;

  const int lin = blockIdx.x;                  // 0..255 = 8*32
  const int sw  = (lin & 7) * 32 + (lin >> 3);
  const int brow = (sw & 15) * 256;
  const int bcol = (sw >> 4) * 256;

  const int sr = tid & 255, sk = tid >> 8;
  const signed char* gA = qh + (size_t)(brow + sr) * I_DIM + sk * 16;
  const signed char* gB = w8 + (size_t)(bcol + sr) * I_DIM + sk * 16;
  const int lA = tid * 16;
  const int lB = 16384 + tid * 16;

  const int ab = (wr * 64 + l31) * 16;
  const int bb = 16384 + (wc * 128 + l31) * 16;

  v16i zero = {0};
  v16i acc[2][4];
  #pragma unroll
  for (int m = 0; m < 2; ++m)
    #pragma unroll
    for (int n = 0; n < 4; ++n) acc[m][n] = zero;

  const int nk = I_DIM / 64;  // 172
  #pragma unroll
  for (int t = 0; t < 3; ++t) {
    gload16(gA + t * 64,      &L[t][lA]);
    gload16(gA + t * 64 + 32, &L[t][lA + 8192]);
    gload16(gB + t * 64,      &L[t][lB]);
    gload16(gB + t * 64 + 32, &L[t][lB + 8192]);
  }

  for (int t = 0; t < nk; ++t) {
    if (t + 2 < nk)      asm volatile("s_waitcnt vmcnt(8)" ::: "memory");
    else if (t + 1 < nk) asm volatile("s_waitcnt vmcnt(4)" ::: "memory");
    else                 asm volatile("s_waitcnt vmcnt(0)" ::: "memory");
    __builtin_amdgcn_s_barrier();
    asm volatile("" ::: "memory");
    const signed char* Lb = L[t & 3];
    signed char* Ls = L[(t + 3) & 3];
    const bool st = (t + 3) < nk;
    const int ko = (t + 3) * 64;

    // ---- phase 0 (ks=0) ----
    {
      v4i af0, af1, bf0, bf1, bf2, bf3;
      af0 = *(const v4i*)&Lb[kgl * 4096 + ab];
      af1 = *(const v4i*)&Lb[kgl * 4096 + ab + 512];
      bf0 = *(const v4i*)&Lb[kgl * 4096 + bb];
      bf1 = *(const v4i*)&Lb[kgl * 4096 + bb + 512];
      bf2 = *(const v4i*)&Lb[kgl * 4096 + bb + 1024];
      bf3 = *(const v4i*)&Lb[kgl * 4096 + bb + 1536];
      if (st) {
        gload16(gA + ko,      &Ls[lA]);
        gload16(gA + ko + 32, &Ls[lA + 8192]);
      }
      __builtin_amdgcn_s_barrier();
      __builtin_amdgcn_s_setprio(1);
      acc[0][0] = MFMA32(af0, bf0, acc[0][0]);
      acc[0][1] = MFMA32(af0, bf1, acc[0][1]);
      acc[0][2] = MFMA32(af0, bf2, acc[0][2]);
      acc[0][3] = MFMA32(af0, bf3, acc[0][3]);
      acc[1][0] = MFMA32(af1, bf0, acc[1][0]);
      acc[1][1] = MFMA32(af1, bf1, acc[1][1]);
      acc[1][2] = MFMA32(af1, bf2, acc[1][2]);
      acc[1][3] = MFMA32(af1, bf3, acc[1][3]);
      __builtin_amdgcn_s_setprio(0);
    }

    // ---- phase 1 (ks=1) ----
    {
      v4i af0, af1, bf0, bf1, bf2, bf3;
      af0 = *(const v4i*)&Lb[(2 + kgl) * 4096 + ab];
      af1 = *(const v4i*)&Lb[(2 + kgl) * 4096 + ab + 512];
      bf0 = *(const v4i*)&Lb[(2 + kgl) * 4096 + bb];
      bf1 = *(const v4i*)&Lb[(2 + kgl) * 4096 + bb + 512];
      bf2 = *(const v4i*)&Lb[(2 + kgl) * 4096 + bb + 1024];
      bf3 = *(const v4i*)&Lb[(2 + kgl) * 4096 + bb + 1536];
      if (st) {
        gload16(gB + ko,      &Ls[lB]);
        gload16(gB + ko + 32, &Ls[lB + 8192]);
      }
      __builtin_amdgcn_s_barrier();
      __builtin_amdgcn_s_setprio(1);
      acc[0][0] = MFMA32(af0, bf0, acc[0][0]);
      acc[0][1] = MFMA32(af0, bf1, acc[0][1]);
      acc[0][2] = MFMA32(af0, bf2, acc[0][2]);
      acc[0][3] = MFMA32(af0, bf3, acc[0][3]);
      acc[1][0] = MFMA32(af1, bf0, acc[1][0]);
      acc[1][1] = MFMA32(af1, bf1, acc[1][1]);
      acc[1][2] = MFMA32(af1, bf2, acc[1][2]);
      acc[1][3] = MFMA32(af1, bf3, acc[1][3]);
      __builtin_amdgcn_s_setprio(0);
    }
  }

  const float hsc = __uint_as_float(scal[1]) * (1.0f / QMAXF);
  #pragma unroll
  for (int m = 0; m < 2; ++m) {
    const int rbase = brow + wr * 64 + m * 32 + 4 * kgl;
    #pragma unroll
    for (int n = 0; n < 4; ++n) {
      const int col = bcol + wc * 128 + n * 32 + l31;
      const float s = sdn[col] * hsc;
      #pragma unroll
      for (int q = 0; q < 16; ++q) {
        const int row = rbase + (q & 3) + 8 * (q >> 2);
        out[(size_t)row * K1 + col] = (float)acc[m][n][q] * s;
      }
    }
  }
}

// ---------------- launch ----------------

extern "C" void kernel_launch(void* const* d_in, const int* in_sizes, int n_in,
                              void* d_out, int out_size, void* d_ws, size_t ws_size,
                              hipStream_t stream) {
  (void)in_sizes; (void)n_in; (void)out_size; (void)ws_size;
  const float* x   = (const float*)d_in[0];
  const float* wgu = (const float*)d_in[1];
  const float* sgu = (const float*)d_in[2];
  const float* wdn = (const float*)d_in[3];
  const float* sdn = (const float*)d_in[4];
  float* out = (float*)d_out;
  char* ws = (char*)d_ws;

  // ws layout (16B aligned): total ~360 MB
  signed char* qx  = (signed char*)(ws + 0LL);           // 16,777,216
  signed char* w8g = (signed char*)(ws + 16777216LL);    // 90,177,536
  signed char* w8d = (signed char*)(ws + 106954752LL);   // 45,088,768
  signed char* qh  = (signed char*)(ws + 152043520LL);   // 45,088,768
  float*       hb  = (float*)      (ws + 197132288LL);   // 180,355,072
  unsigned*    scal= (unsigned*)   (ws + 377487360LL);   // 256

  hipMemsetAsync(scal, 0, 256, stream);
  absmax_x_kernel<<<2048, 256, 0, stream>>>((const float4*)x, scal, T_DIM * K1 / 4);
  quant_x_kernel<<<4096, 256, 0, stream>>>((const float4*)x, (v4i*)qx, scal);
  conv_w_kernel<<<22016, 256, 0, stream>>>((const float4*)wgu, (v4i*)w8g);
  conv_w_kernel<<<11008, 256, 0, stream>>>((const float4*)wdn, (v4i*)w8d);

  gemm1_silu_kernel<<<1376, 512, 0, stream>>>(qx, w8g, sgu, scal, hb);

  quant_h_kernel<<<11008, 256, 0, stream>>>((const float4*)hb, (v4i*)qh, scal,
                                            out + (size_t)T_DIM * K1);

  gemm2_kernel<<<256, 512, 0, stream>>>(qh, w8d, sdn, scal, out);
}